// Round 5
// baseline (24130.684 us; speedup 1.0000x reference)
//
#include <hip/hip_runtime.h>
#include <hip/hip_fp16.h>

#define NDIM 92
#define HDIM 64
#define EDIM 41
#define ZC   128   // 2H
#define CIN  169   // 2H + EDIM
#define NB   1280  // pass-A grid / stats partial rows (5 blocks/CU x 256 CU)

// ---------------------------------------------------------------- embedding
__global__ __launch_bounds__(256) void k_embed(
    const float* __restrict__ nf, const float* __restrict__ W,
    const float* __restrict__ b, float* __restrict__ h, int N)
{
    __shared__ float Wl[NDIM * HDIM];
    __shared__ float nfl[4][NDIM];
    int t = threadIdx.x;
    for (int i = t; i < NDIM * HDIM; i += 256) Wl[i] = W[i];
    int n0 = blockIdx.x * 4;
    for (int i = t; i < 4 * NDIM; i += 256) {
        int slot = i / NDIM, k = i - slot * NDIM;
        int n = n0 + slot;
        nfl[slot][k] = (n < N) ? nf[n * NDIM + k] : 0.f;
    }
    __syncthreads();
    int j = t & 63, slot = t >> 6;
    int n = n0 + slot;
    if (n >= N) return;
    float acc = b[j];
    #pragma unroll
    for (int k = 0; k < NDIM; k++) acc += nfl[slot][k] * Wl[k * HDIM + j];
    h[n * HDIM + j] = acc;
}

// ---------------------------------------------------------------- node GEMM
// PQ[n][c] = sum_k h[n][k] * Wcat[k][c], fp16 table (51 MB, L3-resident)
__global__ __launch_bounds__(256) void k_pq(
    const float* __restrict__ h, const float* __restrict__ Wl,
    __half* __restrict__ PQ, int N)
{
    __shared__ float Wcat[64 * 256];
    __shared__ float hl[32 * 64];
    int t = threadIdx.x;
    for (int i = t; i < 64 * 256; i += 256) {
        int k = i >> 8, c = i & 255;
        Wcat[i] = (c < 128) ? Wl[k * 128 + c] : Wl[(64 + k) * 128 + (c - 128)];
    }
    int jg = t & 63, w = t >> 6;
    int ntiles = (N + 31) >> 5;
    for (int tile = blockIdx.x; tile < ntiles; tile += gridDim.x) {
        int nbase = tile << 5;
        __syncthreads();
        for (int i = t; i < 32 * 64; i += 256) {
            int nn = nbase + (i >> 6);
            hl[i] = (nn < N) ? h[nn * 64 + (i & 63)] : 0.f;
        }
        __syncthreads();
        float acc[8][4];
        #pragma unroll
        for (int n = 0; n < 8; n++)
            acc[n][0] = acc[n][1] = acc[n][2] = acc[n][3] = 0.f;
        for (int k = 0; k < 64; k++) {
            float4 w4 = *(const float4*)&Wcat[k * 256 + jg * 4];
            #pragma unroll
            for (int n = 0; n < 8; n++) {
                float hv = hl[(w * 8 + n) * 64 + k];
                acc[n][0] += hv * w4.x; acc[n][1] += hv * w4.y;
                acc[n][2] += hv * w4.z; acc[n][3] += hv * w4.w;
            }
        }
        #pragma unroll
        for (int n = 0; n < 8; n++) {
            int nn = nbase + w * 8 + n;
            if (nn < N) {
                union { __half2 h2[2]; uint2 u; } pk;
                pk.h2[0] = __floats2half2_rn(acc[n][0], acc[n][1]);
                pk.h2[1] = __floats2half2_rn(acc[n][2], acc[n][3]);
                *(uint2*)&PQ[(size_t)nn * 256 + jg * 4] = pk.u;
            }
        }
    }
}

// ---------------------------------------------------------------- pass A (v5b)
// Register-blocked tile GEMM. Per block-iteration: 32 edges.
//   wave w: edges [(w&1)*16, +16), cols [(w>>1)*64, +64)
//   lane l: eg=l>>4 -> 4 edges, cg=l&15 -> 4 cols  (4x4 register block)
// ef tile staged in LDS via coalesced vector loads; Wbot staged in LDS once.
// Inner 4-k step: 8 ds_read_b128 + 64 FMAs. PQ gathers: 8 ushort4 per
// 16-edge wave-tile, batch-issued. BN partials in registers; reduce at end.
__global__ __launch_bounds__(256, 5) void k_passA(
    const __half* __restrict__ PQ, const float* __restrict__ ef,
    const int* __restrict__ src, const int* __restrict__ dst,
    const float* __restrict__ Wl, const float* __restrict__ bias,
    __half* __restrict__ zh, float* __restrict__ partials, int E)
{
    __shared__ float Wlds[EDIM * 128];   // 20992 B, [k][col]
    __shared__ float eflds[32 * 44];     // 5632 B, rows padded 41->44 for b128
    __shared__ int   sdlds[64];          // src[0..31], dst[32..63]
    __shared__ float redS[256];
    __shared__ float redQ[256];

    int t = threadIdx.x;
    int lane = t & 63;
    int wv = t >> 6;                 // 0..3
    int eg = lane >> 4;              // 0..3: edge group
    int cg = lane & 15;              // 0..15: col group
    int ebase = (wv & 1) * 16;       // wave's edge offset in tile
    int wcol  = (wv >> 1) * 64 + cg * 4;   // wave's first col for this lane

    const float* Wbot = Wl + 128 * 128;    // rows 128..168, layout [41][128]
    for (int i = t; i < EDIM * 128; i += 256) Wlds[i] = Wbot[i];

    float4 b4 = *(const float4*)&bias[wcol];

    const unsigned char*  pqb = (const unsigned char*)PQ;
    unsigned short*       zs  = (unsigned short*)zh;

    float psum4[4] = {0.f, 0.f, 0.f, 0.f};
    float psq4[4]  = {0.f, 0.f, 0.f, 0.f};

    int ntiles = (E + 31) >> 5;
    for (int tile = blockIdx.x; tile < ntiles; tile += gridDim.x) {
        int e0 = tile << 5;
        __syncthreads();
        // ---- stage ef tile: contiguous global -> padded LDS rows
        {
            size_t gbase = (size_t)e0 * EDIM;
            size_t glim  = (size_t)E * EDIM;
            for (int idx = t; idx < 32 * EDIM; idx += 256) {
                int er = idx / EDIM, k = idx - er * EDIM;
                size_t g = gbase + idx;
                eflds[er * 44 + k] = (g < glim) ? ef[g] : 0.f;
            }
            if (t < 32)       sdlds[t]      = (e0 + t      < E) ? src[e0 + t]      : 0;
            else if (t < 64)  sdlds[t]      = (e0 + t - 32 < E) ? dst[e0 + t - 32] : 0;
        }
        __syncthreads();

        // ---- 4x4 register-blocked GEMM over k
        float4 acc0 = {0,0,0,0}, acc1 = {0,0,0,0}, acc2 = {0,0,0,0}, acc3 = {0,0,0,0};
        int er0 = (ebase + eg * 4) * 44;
        #pragma unroll
        for (int k0 = 0; k0 < 40; k0 += 4) {
            float4 w0 = *(const float4*)&Wlds[(k0 + 0) * 128 + wcol];
            float4 w1 = *(const float4*)&Wlds[(k0 + 1) * 128 + wcol];
            float4 w2 = *(const float4*)&Wlds[(k0 + 2) * 128 + wcol];
            float4 w3 = *(const float4*)&Wlds[(k0 + 3) * 128 + wcol];
            float4 f0 = *(const float4*)&eflds[er0 + k0];
            float4 f1 = *(const float4*)&eflds[er0 + 44 + k0];
            float4 f2 = *(const float4*)&eflds[er0 + 88 + k0];
            float4 f3 = *(const float4*)&eflds[er0 + 132 + k0];
            acc0.x += f0.x*w0.x + f0.y*w1.x + f0.z*w2.x + f0.w*w3.x;
            acc0.y += f0.x*w0.y + f0.y*w1.y + f0.z*w2.y + f0.w*w3.y;
            acc0.z += f0.x*w0.z + f0.y*w1.z + f0.z*w2.z + f0.w*w3.z;
            acc0.w += f0.x*w0.w + f0.y*w1.w + f0.z*w2.w + f0.w*w3.w;
            acc1.x += f1.x*w0.x + f1.y*w1.x + f1.z*w2.x + f1.w*w3.x;
            acc1.y += f1.x*w0.y + f1.y*w1.y + f1.z*w2.y + f1.w*w3.y;
            acc1.z += f1.x*w0.z + f1.y*w1.z + f1.z*w2.z + f1.w*w3.z;
            acc1.w += f1.x*w0.w + f1.y*w1.w + f1.z*w2.w + f1.w*w3.w;
            acc2.x += f2.x*w0.x + f2.y*w1.x + f2.z*w2.x + f2.w*w3.x;
            acc2.y += f2.x*w0.y + f2.y*w1.y + f2.z*w2.y + f2.w*w3.y;
            acc2.z += f2.x*w0.z + f2.y*w1.z + f2.z*w2.z + f2.w*w3.z;
            acc2.w += f2.x*w0.w + f2.y*w1.w + f2.z*w2.w + f2.w*w3.w;
            acc3.x += f3.x*w0.x + f3.y*w1.x + f3.z*w2.x + f3.w*w3.x;
            acc3.y += f3.x*w0.y + f3.y*w1.y + f3.z*w2.y + f3.w*w3.y;
            acc3.z += f3.x*w0.z + f3.y*w1.z + f3.z*w2.z + f3.w*w3.z;
            acc3.w += f3.x*w0.w + f3.y*w1.w + f3.z*w2.w + f3.w*w3.w;
        }
        {   // k = 40 tail
            float4 w4 = *(const float4*)&Wlds[40 * 128 + wcol];
            float fa = eflds[er0 + 40], fb = eflds[er0 + 84],
                  fc = eflds[er0 + 128], fd = eflds[er0 + 172];
            acc0.x += fa*w4.x; acc0.y += fa*w4.y; acc0.z += fa*w4.z; acc0.w += fa*w4.w;
            acc1.x += fb*w4.x; acc1.y += fb*w4.y; acc1.z += fb*w4.z; acc1.w += fb*w4.w;
            acc2.x += fc*w4.x; acc2.y += fc*w4.y; acc2.z += fc*w4.z; acc2.w += fc*w4.w;
            acc3.x += fd*w4.x; acc3.y += fd*w4.y; acc3.z += fd*w4.z; acc3.w += fd*w4.w;
        }

        // ---- gathers: batch-issue all 8 (4 src + 4 dst) for MLP
        int el0 = ebase + eg * 4;
        int s0 = sdlds[el0], s1 = sdlds[el0 + 1], s2 = sdlds[el0 + 2], s3 = sdlds[el0 + 3];
        int d0 = sdlds[32 + el0], d1 = sdlds[32 + el0 + 1],
            d2 = sdlds[32 + el0 + 2], d3 = sdlds[32 + el0 + 3];
        size_t co = (size_t)wcol * 2;
        ushort4 gs0 = *(const ushort4*)(pqb + (size_t)s0 * 512 + co);
        ushort4 gs1 = *(const ushort4*)(pqb + (size_t)s1 * 512 + co);
        ushort4 gs2 = *(const ushort4*)(pqb + (size_t)s2 * 512 + co);
        ushort4 gs3 = *(const ushort4*)(pqb + (size_t)s3 * 512 + co);
        ushort4 gd0 = *(const ushort4*)(pqb + (size_t)d0 * 512 + 256 + co);
        ushort4 gd1 = *(const ushort4*)(pqb + (size_t)d1 * 512 + 256 + co);
        ushort4 gd2 = *(const ushort4*)(pqb + (size_t)d2 * 512 + 256 + co);
        ushort4 gd3 = *(const ushort4*)(pqb + (size_t)d3 * 512 + 256 + co);

        #pragma unroll
        for (int i = 0; i < 4; i++) {
            int e = e0 + el0 + i;
            if (e >= E) break;
            float4 a = (i == 0) ? acc0 : (i == 1) ? acc1 : (i == 2) ? acc2 : acc3;
            ushort4 gs = (i == 0) ? gs0 : (i == 1) ? gs1 : (i == 2) ? gs2 : gs3;
            ushort4 gd = (i == 0) ? gd0 : (i == 1) ? gd1 : (i == 2) ? gd2 : gd3;
            float z0 = a.x + b4.x + __half2float(__ushort_as_half(gs.x))
                                  + __half2float(__ushort_as_half(gd.x));
            float z1 = a.y + b4.y + __half2float(__ushort_as_half(gs.y))
                                  + __half2float(__ushort_as_half(gd.y));
            float z2 = a.z + b4.z + __half2float(__ushort_as_half(gs.z))
                                  + __half2float(__ushort_as_half(gd.z));
            float z3 = a.w + b4.w + __half2float(__ushort_as_half(gs.w))
                                  + __half2float(__ushort_as_half(gd.w));
            psum4[0] += z0; psum4[1] += z1; psum4[2] += z2; psum4[3] += z3;
            psq4[0] += z0*z0; psq4[1] += z1*z1; psq4[2] += z2*z2; psq4[3] += z3*z3;
            // pack 4 halves into one 64-bit word; nontemporal builtin needs a
            // scalar-int pointer (HIP uint2* is a class type -> rejected)
            union { __half2 h2[2]; unsigned long long u; } pk;
            pk.h2[0] = __floats2half2_rn(z0, z1);
            pk.h2[1] = __floats2half2_rn(z2, z3);
            __builtin_nontemporal_store(pk.u,
                (unsigned long long*)(zs + (size_t)e * 128 + wcol));
        }
    }

    // ---- final stats reduction: butterfly over eg, then LDS across waves
    #pragma unroll
    for (int j = 0; j < 4; j++) {
        psum4[j] += __shfl_xor(psum4[j], 16);
        psum4[j] += __shfl_xor(psum4[j], 32);
        psq4[j]  += __shfl_xor(psq4[j], 16);
        psq4[j]  += __shfl_xor(psq4[j], 32);
    }
    if (eg == 0) {
        int half = (wv & 1) * 128;
        #pragma unroll
        for (int j = 0; j < 4; j++) {
            redS[half + wcol + j] = psum4[j];
            redQ[half + wcol + j] = psq4[j];
        }
    }
    __syncthreads();
    if (t < 128) {
        partials[blockIdx.x * 256 + t]       = redS[t] + redS[128 + t];
        partials[blockIdx.x * 256 + 128 + t] = redQ[t] + redQ[128 + t];
    }
}

// ---------------------------------------------------------------- stats
__global__ __launch_bounds__(256) void k_red1(
    const float* __restrict__ partials, float* __restrict__ p2, int nb)
{
    int t = threadIdx.x, r = blockIdx.x;
    int per = (nb + 63) / 64;
    float s = 0.f;
    int b0 = r * per, b1 = b0 + per; if (b1 > nb) b1 = nb;
    for (int b = b0; b < b1; b++) s += partials[b * 256 + t];
    p2[r * 256 + t] = s;
}

__global__ __launch_bounds__(256) void k_bnstats(
    const float* __restrict__ p2, const float* __restrict__ gamma,
    const float* __restrict__ beta, float* __restrict__ bnA,
    float* __restrict__ bnC, int R, float invE)
{
    int t = threadIdx.x;
    float s = 0.f;
    for (int r = 0; r < R; r++) s += p2[r * 256 + t];
    __shared__ float red[256];
    red[t] = s;
    __syncthreads();
    if (t < 128) {
        float mean = red[t] * invE;
        float var  = red[128 + t] * invE - mean * mean;
        float a = gamma[t] * rsqrtf(var + 1e-5f);
        bnA[t] = a;
        bnC[t] = beta[t] - mean * a;
    }
}

// ---------------------------------------------------------------- pass B
__global__ __launch_bounds__(256) void k_passB(
    const __half* __restrict__ zh, const int* __restrict__ src,
    const float* __restrict__ bnA, const float* __restrict__ bnC,
    float* __restrict__ h, int E)
{
    int t = threadIdx.x;
    int j = t & 63, slot = t >> 6;
    float a0 = bnA[j],      c0 = bnC[j];
    float a1 = bnA[64 + j], c1 = bnC[64 + j];
    const unsigned short* zs = (const unsigned short*)zh;
    for (int e = blockIdx.x * 4 + slot; e < E; e += gridDim.x * 4) {
        float za = __half2float(__ushort_as_half(
            __builtin_nontemporal_load(zs + (size_t)e * 128 + j)))      * a0 + c0;
        float zb = __half2float(__ushort_as_half(
            __builtin_nontemporal_load(zs + (size_t)e * 128 + 64 + j))) * a1 + c1;
        float sig = 1.f / (1.f + __expf(-za));
        float sp  = fmaxf(zb, 0.f) + log1pf(__expf(-fabsf(zb)));
        atomicAdd(&h[src[e] * 64 + j], sig * sp);
    }
}

// ---------------------------------------------------------------- pooling
__global__ __launch_bounds__(256) void k_pool(
    const float* __restrict__ h, const int* __restrict__ gid,
    float* __restrict__ pool, float* __restrict__ cnt, int N)
{
    int t = threadIdx.x;
    int j = t & 63, slot = t >> 6;
    int n = blockIdx.x * 4 + slot;
    if (n >= N) return;
    int g = gid[n];
    atomicAdd(&pool[g * 64 + j], h[n * 64 + j]);
    if (j == 0) atomicAdd(&cnt[g], 1.f);
}

// ---------------------------------------------------------------- head
__global__ __launch_bounds__(128) void k_head(
    const float* __restrict__ pool, const float* __restrict__ cnt,
    const float* __restrict__ fcW, const float* __restrict__ fcb,
    const float* __restrict__ outW, const float* __restrict__ outb,
    float* __restrict__ out, int G)
{
    int g = blockIdx.x, t = threadIdx.x;
    __shared__ float pl[64];
    if (t < 64) pl[t] = pool[g * 64 + t] / fmaxf(cnt[g], 1.f);
    __syncthreads();
    float acc = fcb[t];
    #pragma unroll
    for (int k = 0; k < 64; k++) acc += pl[k] * fcW[k * 128 + t];
    float sp = fmaxf(acc, 0.f) + log1pf(__expf(-fabsf(acc)));
    float v = sp * outW[t];
    __shared__ float red[128];
    red[t] = v;
    __syncthreads();
    for (int s = 64; s > 0; s >>= 1) {
        if (t < s) red[t] += red[t + s];
        __syncthreads();
    }
    if (t == 0) out[g] = red[0] + outb[0];
}

// ---------------------------------------------------------------- launcher
extern "C" void kernel_launch(void* const* d_in, const int* in_sizes, int n_in,
                              void* d_out, int out_size, void* d_ws, size_t ws_size,
                              hipStream_t stream)
{
    const float* nf    = (const float*)d_in[0];
    const int*   ei    = (const int*)d_in[1];
    const float* ef    = (const float*)d_in[2];
    const int*   gid   = (const int*)d_in[3];
    const float* embW  = (const float*)d_in[4];
    const float* embB  = (const float*)d_in[5];
    const float* convW = (const float*)d_in[6];
    const float* convB = (const float*)d_in[7];
    const float* gam   = (const float*)d_in[8];
    const float* bet   = (const float*)d_in[9];
    const float* fcW   = (const float*)d_in[10];
    const float* fcb   = (const float*)d_in[11];
    const float* outW  = (const float*)d_in[12];
    const float* outb  = (const float*)d_in[13];
    float* out = (float*)d_out;

    int N = in_sizes[0] / NDIM;
    int E = in_sizes[1] / 2;
    int G = out_size;
    const int* src = ei;
    const int* dst = ei + E;

    char* ws = (char*)d_ws;
    size_t off = 0;
    auto alloc = [&](size_t bytes) {
        void* p = ws + off;
        off = (off + bytes + 255) & ~(size_t)255;
        return p;
    };
    float*  h        = (float*)alloc((size_t)N * 64 * 4);
    __half* PQ       = (__half*)alloc((size_t)N * 256 * 2);
    __half* zh       = (__half*)alloc((size_t)E * 128 * 2);
    float*  partials = (float*)alloc((size_t)NB * 256 * 4);
    float*  p2       = (float*)alloc((size_t)64 * 256 * 4);
    float*  bnA      = (float*)alloc(128 * 4);
    float*  bnC      = (float*)alloc(128 * 4);
    float*  pool     = (float*)alloc((size_t)G * 65 * 4);  // sums + counts
    float*  cnt      = pool + (size_t)G * 64;

    k_embed<<<(N + 3) / 4, 256, 0, stream>>>(nf, embW, embB, h, N);

    for (int l = 0; l < 3; l++) {
        const float* Wl = convW + (size_t)l * CIN * ZC;
        k_pq<<<1024, 256, 0, stream>>>(h, Wl, PQ, N);
        k_passA<<<NB, 256, 0, stream>>>(PQ, ef, src, dst, Wl, convB + l * ZC,
                                        zh, partials, E);
        k_red1<<<64, 256, 0, stream>>>(partials, p2, NB);
        k_bnstats<<<1, 256, 0, stream>>>(p2, gam + l * ZC, bet + l * ZC,
                                         bnA, bnC, 64, 1.f / (float)E);
        k_passB<<<4096, 256, 0, stream>>>(zh, src, bnA, bnC, h, E);
    }

    hipMemsetAsync(pool, 0, (size_t)G * 65 * 4, stream);
    k_pool<<<(N + 3) / 4, 256, 0, stream>>>(h, gid, pool, cnt, N);
    k_head<<<G, 128, 0, stream>>>(pool, cnt, fcW, fcb, outW, outb, out, G);
}

// Round 6
// 4412.936 us; speedup vs baseline: 5.4682x; 5.4682x over previous
//
#include <hip/hip_runtime.h>
#include <hip/hip_fp16.h>

#define NDIM 92
#define HDIM 64
#define EDIM 41
#define ZC   128   // 2H
#define CIN  169   // 2H + EDIM
#define NB   1280  // pass-A grid / stats partial rows

// ---------------------------------------------------------------- embedding
__global__ __launch_bounds__(256) void k_embed(
    const float* __restrict__ nf, const float* __restrict__ W,
    const float* __restrict__ b, float* __restrict__ h, int N)
{
    __shared__ float Wl[NDIM * HDIM];
    __shared__ float nfl[4][NDIM];
    int t = threadIdx.x;
    for (int i = t; i < NDIM * HDIM; i += 256) Wl[i] = W[i];
    int n0 = blockIdx.x * 4;
    for (int i = t; i < 4 * NDIM; i += 256) {
        int slot = i / NDIM, k = i - slot * NDIM;
        int n = n0 + slot;
        nfl[slot][k] = (n < N) ? nf[n * NDIM + k] : 0.f;
    }
    __syncthreads();
    int j = t & 63, slot = t >> 6;
    int n = n0 + slot;
    if (n >= N) return;
    float acc = b[j];
    #pragma unroll
    for (int k = 0; k < NDIM; k++) acc += nfl[slot][k] * Wl[k * HDIM + j];
    h[n * HDIM + j] = acc;
}

// ---------------------------------------------------------------- node GEMM
// PQ[n][c] = sum_k h[n][k] * Wcat[k][c], fp16 table (51 MB, L3-resident)
__global__ __launch_bounds__(256) void k_pq(
    const float* __restrict__ h, const float* __restrict__ Wl,
    __half* __restrict__ PQ, int N)
{
    __shared__ float Wcat[64 * 256];
    __shared__ float hl[32 * 64];
    int t = threadIdx.x;
    for (int i = t; i < 64 * 256; i += 256) {
        int k = i >> 8, c = i & 255;
        Wcat[i] = (c < 128) ? Wl[k * 128 + c] : Wl[(64 + k) * 128 + (c - 128)];
    }
    int jg = t & 63, w = t >> 6;
    int ntiles = (N + 31) >> 5;
    for (int tile = blockIdx.x; tile < ntiles; tile += gridDim.x) {
        int nbase = tile << 5;
        __syncthreads();
        for (int i = t; i < 32 * 64; i += 256) {
            int nn = nbase + (i >> 6);
            hl[i] = (nn < N) ? h[nn * 64 + (i & 63)] : 0.f;
        }
        __syncthreads();
        float acc[8][4];
        #pragma unroll
        for (int n = 0; n < 8; n++)
            acc[n][0] = acc[n][1] = acc[n][2] = acc[n][3] = 0.f;
        for (int k = 0; k < 64; k++) {
            float4 w4 = *(const float4*)&Wcat[k * 256 + jg * 4];
            #pragma unroll
            for (int n = 0; n < 8; n++) {
                float hv = hl[(w * 8 + n) * 64 + k];
                acc[n][0] += hv * w4.x; acc[n][1] += hv * w4.y;
                acc[n][2] += hv * w4.z; acc[n][3] += hv * w4.w;
            }
        }
        #pragma unroll
        for (int n = 0; n < 8; n++) {
            int nn = nbase + w * 8 + n;
            if (nn < N) {
                union { __half2 h2[2]; uint2 u; } pk;
                pk.h2[0] = __floats2half2_rn(acc[n][0], acc[n][1]);
                pk.h2[1] = __floats2half2_rn(acc[n][2], acc[n][3]);
                *(uint2*)&PQ[(size_t)nn * 256 + jg * 4] = pk.u;
            }
        }
    }
}

// ---------------------------------------------------------------- pass A (v6)
// Register-blocked tile GEMM, 32 edges per block-iteration.
//   wave w: edges [(w&1)*16, +16), cols [(w>>1)*64, +64)
//   lane l: eg=l>>4 -> 4 edges, cg=l&15 -> 4 cols  (4x4 register block)
// v5 post-mortem: __launch_bounds__(256,5) capped VGPRs at 48 -> the ~90-reg
// live set spilled to scratch INSIDE the k-loop -> 28 GB/dispatch of scratch
// traffic, 7400us. Fix: (256,2) lifts the cap to 256 (LDS still allows 5
// blocks/CU; VGPRs will settle ~3-4), and the k-loop is restructured to 2-k
// steps (16 transient regs instead of 32) so the live set fits comfortably.
__global__ __launch_bounds__(256, 2) void k_passA(
    const __half* __restrict__ PQ, const float* __restrict__ ef,
    const int* __restrict__ src, const int* __restrict__ dst,
    const float* __restrict__ Wl, const float* __restrict__ bias,
    __half* __restrict__ zh, float* __restrict__ partials, int E)
{
    __shared__ float Wlds[EDIM * 128];   // 20992 B, [k][col]
    __shared__ float eflds[32 * 44];     // 5632 B, rows padded 41->44
    __shared__ int   sdlds[64];          // src[0..31], dst[32..63]
    __shared__ float redS[256];
    __shared__ float redQ[256];

    int t = threadIdx.x;
    int lane = t & 63;
    int wv = t >> 6;                 // 0..3
    int eg = lane >> 4;              // 0..3: edge group
    int cg = lane & 15;              // 0..15: col group
    int ebase = (wv & 1) * 16;       // wave's edge offset in tile
    int wcol  = (wv >> 1) * 64 + cg * 4;   // wave's first col for this lane

    const float* Wbot = Wl + 128 * 128;    // rows 128..168, layout [41][128]
    for (int i = t; i < EDIM * 128; i += 256) Wlds[i] = Wbot[i];

    float4 b4 = *(const float4*)&bias[wcol];

    const unsigned char*  pqb = (const unsigned char*)PQ;
    unsigned short*       zs  = (unsigned short*)zh;

    float psum4[4] = {0.f, 0.f, 0.f, 0.f};
    float psq4[4]  = {0.f, 0.f, 0.f, 0.f};

    int ntiles = (E + 31) >> 5;
    for (int tile = blockIdx.x; tile < ntiles; tile += gridDim.x) {
        int e0 = tile << 5;
        __syncthreads();
        // ---- stage ef tile: contiguous global -> padded LDS rows
        {
            size_t gbase = (size_t)e0 * EDIM;
            size_t glim  = (size_t)E * EDIM;
            for (int idx = t; idx < 32 * EDIM; idx += 256) {
                int er = idx / EDIM, k = idx - er * EDIM;
                size_t g = gbase + idx;
                eflds[er * 44 + k] = (g < glim) ? ef[g] : 0.f;
            }
            if (t < 32)       sdlds[t] = (e0 + t      < E) ? src[e0 + t]      : 0;
            else if (t < 64)  sdlds[t] = (e0 + t - 32 < E) ? dst[e0 + t - 32] : 0;
        }
        __syncthreads();

        // ---- 4x4 register-blocked GEMM over k (2-k steps, low reg pressure)
        float4 acc0 = {0,0,0,0}, acc1 = {0,0,0,0}, acc2 = {0,0,0,0}, acc3 = {0,0,0,0};
        int er0 = (ebase + eg * 4) * 44;
        #pragma unroll
        for (int k0 = 0; k0 < 40; k0 += 2) {
            float4 w0 = *(const float4*)&Wlds[(k0 + 0) * 128 + wcol];
            float4 w1 = *(const float4*)&Wlds[(k0 + 1) * 128 + wcol];
            float2 f0 = *(const float2*)&eflds[er0 + k0];
            float2 f1 = *(const float2*)&eflds[er0 + 44 + k0];
            float2 f2 = *(const float2*)&eflds[er0 + 88 + k0];
            float2 f3 = *(const float2*)&eflds[er0 + 132 + k0];
            acc0.x += f0.x*w0.x + f0.y*w1.x;
            acc0.y += f0.x*w0.y + f0.y*w1.y;
            acc0.z += f0.x*w0.z + f0.y*w1.z;
            acc0.w += f0.x*w0.w + f0.y*w1.w;
            acc1.x += f1.x*w0.x + f1.y*w1.x;
            acc1.y += f1.x*w0.y + f1.y*w1.y;
            acc1.z += f1.x*w0.z + f1.y*w1.z;
            acc1.w += f1.x*w0.w + f1.y*w1.w;
            acc2.x += f2.x*w0.x + f2.y*w1.x;
            acc2.y += f2.x*w0.y + f2.y*w1.y;
            acc2.z += f2.x*w0.z + f2.y*w1.z;
            acc2.w += f2.x*w0.w + f2.y*w1.w;
            acc3.x += f3.x*w0.x + f3.y*w1.x;
            acc3.y += f3.x*w0.y + f3.y*w1.y;
            acc3.z += f3.x*w0.z + f3.y*w1.z;
            acc3.w += f3.x*w0.w + f3.y*w1.w;
        }
        {   // k = 40 tail
            float4 w4 = *(const float4*)&Wlds[40 * 128 + wcol];
            float fa = eflds[er0 + 40], fb = eflds[er0 + 84],
                  fc = eflds[er0 + 128], fd = eflds[er0 + 172];
            acc0.x += fa*w4.x; acc0.y += fa*w4.y; acc0.z += fa*w4.z; acc0.w += fa*w4.w;
            acc1.x += fb*w4.x; acc1.y += fb*w4.y; acc1.z += fb*w4.z; acc1.w += fb*w4.w;
            acc2.x += fc*w4.x; acc2.y += fc*w4.y; acc2.z += fc*w4.z; acc2.w += fc*w4.w;
            acc3.x += fd*w4.x; acc3.y += fd*w4.y; acc3.z += fd*w4.z; acc3.w += fd*w4.w;
        }

        // ---- gathers: batch-issue all 8 (4 src + 4 dst) for MLP
        int el0 = ebase + eg * 4;
        int s0 = sdlds[el0], s1 = sdlds[el0 + 1], s2 = sdlds[el0 + 2], s3 = sdlds[el0 + 3];
        int d0 = sdlds[32 + el0], d1 = sdlds[32 + el0 + 1],
            d2 = sdlds[32 + el0 + 2], d3 = sdlds[32 + el0 + 3];
        size_t co = (size_t)wcol * 2;
        ushort4 gs0 = *(const ushort4*)(pqb + (size_t)s0 * 512 + co);
        ushort4 gs1 = *(const ushort4*)(pqb + (size_t)s1 * 512 + co);
        ushort4 gs2 = *(const ushort4*)(pqb + (size_t)s2 * 512 + co);
        ushort4 gs3 = *(const ushort4*)(pqb + (size_t)s3 * 512 + co);
        ushort4 gd0 = *(const ushort4*)(pqb + (size_t)d0 * 512 + 256 + co);
        ushort4 gd1 = *(const ushort4*)(pqb + (size_t)d1 * 512 + 256 + co);
        ushort4 gd2 = *(const ushort4*)(pqb + (size_t)d2 * 512 + 256 + co);
        ushort4 gd3 = *(const ushort4*)(pqb + (size_t)d3 * 512 + 256 + co);

        #pragma unroll
        for (int i = 0; i < 4; i++) {
            int e = e0 + el0 + i;
            if (e >= E) break;
            float4 a = (i == 0) ? acc0 : (i == 1) ? acc1 : (i == 2) ? acc2 : acc3;
            ushort4 gs = (i == 0) ? gs0 : (i == 1) ? gs1 : (i == 2) ? gs2 : gs3;
            ushort4 gd = (i == 0) ? gd0 : (i == 1) ? gd1 : (i == 2) ? gd2 : gd3;
            float z0 = a.x + b4.x + __half2float(__ushort_as_half(gs.x))
                                  + __half2float(__ushort_as_half(gd.x));
            float z1 = a.y + b4.y + __half2float(__ushort_as_half(gs.y))
                                  + __half2float(__ushort_as_half(gd.y));
            float z2 = a.z + b4.z + __half2float(__ushort_as_half(gs.z))
                                  + __half2float(__ushort_as_half(gd.z));
            float z3 = a.w + b4.w + __half2float(__ushort_as_half(gs.w))
                                  + __half2float(__ushort_as_half(gd.w));
            psum4[0] += z0; psum4[1] += z1; psum4[2] += z2; psum4[3] += z3;
            psq4[0] += z0*z0; psq4[1] += z1*z1; psq4[2] += z2*z2; psq4[3] += z3*z3;
            union { __half2 h2[2]; unsigned long long u; } pk;
            pk.h2[0] = __floats2half2_rn(z0, z1);
            pk.h2[1] = __floats2half2_rn(z2, z3);
            __builtin_nontemporal_store(pk.u,
                (unsigned long long*)(zs + (size_t)e * 128 + wcol));
        }
    }

    // ---- final stats reduction: butterfly over eg, then LDS across waves
    #pragma unroll
    for (int j = 0; j < 4; j++) {
        psum4[j] += __shfl_xor(psum4[j], 16);
        psum4[j] += __shfl_xor(psum4[j], 32);
        psq4[j]  += __shfl_xor(psq4[j], 16);
        psq4[j]  += __shfl_xor(psq4[j], 32);
    }
    if (eg == 0) {
        int half = (wv & 1) * 128;
        #pragma unroll
        for (int j = 0; j < 4; j++) {
            redS[half + wcol + j] = psum4[j];
            redQ[half + wcol + j] = psq4[j];
        }
    }
    __syncthreads();
    if (t < 128) {
        partials[blockIdx.x * 256 + t]       = redS[t] + redS[128 + t];
        partials[blockIdx.x * 256 + 128 + t] = redQ[t] + redQ[128 + t];
    }
}

// ---------------------------------------------------------------- stats
__global__ __launch_bounds__(256) void k_red1(
    const float* __restrict__ partials, float* __restrict__ p2, int nb)
{
    int t = threadIdx.x, r = blockIdx.x;
    int per = (nb + 63) / 64;
    float s = 0.f;
    int b0 = r * per, b1 = b0 + per; if (b1 > nb) b1 = nb;
    for (int b = b0; b < b1; b++) s += partials[b * 256 + t];
    p2[r * 256 + t] = s;
}

__global__ __launch_bounds__(256) void k_bnstats(
    const float* __restrict__ p2, const float* __restrict__ gamma,
    const float* __restrict__ beta, float* __restrict__ bnA,
    float* __restrict__ bnC, int R, float invE)
{
    int t = threadIdx.x;
    float s = 0.f;
    for (int r = 0; r < R; r++) s += p2[r * 256 + t];
    __shared__ float red[256];
    red[t] = s;
    __syncthreads();
    if (t < 128) {
        float mean = red[t] * invE;
        float var  = red[128 + t] * invE - mean * mean;
        float a = gamma[t] * rsqrtf(var + 1e-5f);
        bnA[t] = a;
        bnC[t] = beta[t] - mean * a;
    }
}

// ---------------------------------------------------------------- pass B
__global__ __launch_bounds__(256) void k_passB(
    const __half* __restrict__ zh, const int* __restrict__ src,
    const float* __restrict__ bnA, const float* __restrict__ bnC,
    float* __restrict__ h, int E)
{
    int t = threadIdx.x;
    int j = t & 63, slot = t >> 6;
    float a0 = bnA[j],      c0 = bnC[j];
    float a1 = bnA[64 + j], c1 = bnC[64 + j];
    const unsigned short* zs = (const unsigned short*)zh;
    for (int e = blockIdx.x * 4 + slot; e < E; e += gridDim.x * 4) {
        float za = __half2float(__ushort_as_half(
            __builtin_nontemporal_load(zs + (size_t)e * 128 + j)))      * a0 + c0;
        float zb = __half2float(__ushort_as_half(
            __builtin_nontemporal_load(zs + (size_t)e * 128 + 64 + j))) * a1 + c1;
        float sig = 1.f / (1.f + __expf(-za));
        float sp  = fmaxf(zb, 0.f) + log1pf(__expf(-fabsf(zb)));
        atomicAdd(&h[src[e] * 64 + j], sig * sp);
    }
}

// ---------------------------------------------------------------- pooling
__global__ __launch_bounds__(256) void k_pool(
    const float* __restrict__ h, const int* __restrict__ gid,
    float* __restrict__ pool, float* __restrict__ cnt, int N)
{
    int t = threadIdx.x;
    int j = t & 63, slot = t >> 6;
    int n = blockIdx.x * 4 + slot;
    if (n >= N) return;
    int g = gid[n];
    atomicAdd(&pool[g * 64 + j], h[n * 64 + j]);
    if (j == 0) atomicAdd(&cnt[g], 1.f);
}

// ---------------------------------------------------------------- head
__global__ __launch_bounds__(128) void k_head(
    const float* __restrict__ pool, const float* __restrict__ cnt,
    const float* __restrict__ fcW, const float* __restrict__ fcb,
    const float* __restrict__ outW, const float* __restrict__ outb,
    float* __restrict__ out, int G)
{
    int g = blockIdx.x, t = threadIdx.x;
    __shared__ float pl[64];
    if (t < 64) pl[t] = pool[g * 64 + t] / fmaxf(cnt[g], 1.f);
    __syncthreads();
    float acc = fcb[t];
    #pragma unroll
    for (int k = 0; k < 64; k++) acc += pl[k] * fcW[k * 128 + t];
    float sp = fmaxf(acc, 0.f) + log1pf(__expf(-fabsf(acc)));
    float v = sp * outW[t];
    __shared__ float red[128];
    red[t] = v;
    __syncthreads();
    for (int s = 64; s > 0; s >>= 1) {
        if (t < s) red[t] += red[t + s];
        __syncthreads();
    }
    if (t == 0) out[g] = red[0] + outb[0];
}

// ---------------------------------------------------------------- launcher
extern "C" void kernel_launch(void* const* d_in, const int* in_sizes, int n_in,
                              void* d_out, int out_size, void* d_ws, size_t ws_size,
                              hipStream_t stream)
{
    const float* nf    = (const float*)d_in[0];
    const int*   ei    = (const int*)d_in[1];
    const float* ef    = (const float*)d_in[2];
    const int*   gid   = (const int*)d_in[3];
    const float* embW  = (const float*)d_in[4];
    const float* embB  = (const float*)d_in[5];
    const float* convW = (const float*)d_in[6];
    const float* convB = (const float*)d_in[7];
    const float* gam   = (const float*)d_in[8];
    const float* bet   = (const float*)d_in[9];
    const float* fcW   = (const float*)d_in[10];
    const float* fcb   = (const float*)d_in[11];
    const float* outW  = (const float*)d_in[12];
    const float* outb  = (const float*)d_in[13];
    float* out = (float*)d_out;

    int N = in_sizes[0] / NDIM;
    int E = in_sizes[1] / 2;
    int G = out_size;
    const int* src = ei;
    const int* dst = ei + E;

    char* ws = (char*)d_ws;
    size_t off = 0;
    auto alloc = [&](size_t bytes) {
        void* p = ws + off;
        off = (off + bytes + 255) & ~(size_t)255;
        return p;
    };
    float*  h        = (float*)alloc((size_t)N * 64 * 4);
    __half* PQ       = (__half*)alloc((size_t)N * 256 * 2);
    __half* zh       = (__half*)alloc((size_t)E * 128 * 2);
    float*  partials = (float*)alloc((size_t)NB * 256 * 4);
    float*  p2       = (float*)alloc((size_t)64 * 256 * 4);
    float*  bnA      = (float*)alloc(128 * 4);
    float*  bnC      = (float*)alloc(128 * 4);
    float*  pool     = (float*)alloc((size_t)G * 65 * 4);  // sums + counts
    float*  cnt      = pool + (size_t)G * 64;

    k_embed<<<(N + 3) / 4, 256, 0, stream>>>(nf, embW, embB, h, N);

    for (int l = 0; l < 3; l++) {
        const float* Wl = convW + (size_t)l * CIN * ZC;
        k_pq<<<1024, 256, 0, stream>>>(h, Wl, PQ, N);
        k_passA<<<NB, 256, 0, stream>>>(PQ, ef, src, dst, Wl, convB + l * ZC,
                                        zh, partials, E);
        k_red1<<<64, 256, 0, stream>>>(partials, p2, NB);
        k_bnstats<<<1, 256, 0, stream>>>(p2, gam + l * ZC, bet + l * ZC,
                                         bnA, bnC, 64, 1.f / (float)E);
        k_passB<<<4096, 256, 0, stream>>>(zh, src, bnA, bnC, h, E);
    }

    hipMemsetAsync(pool, 0, (size_t)G * 65 * 4, stream);
    k_pool<<<(N + 3) / 4, 256, 0, stream>>>(h, gid, pool, cnt, N);
    k_head<<<G, 128, 0, stream>>>(pool, cnt, fcW, fcb, outW, outb, out, G);
}